// Round 18
// baseline (154.577 us; speedup 1.0000x reference)
//
#include <hip/hip_runtime.h>
#include <hip/hip_bf16.h>

// B=4, C=128, H=W=64 -> N=4096. ALL I/O FP32.
// Round 23: R19's intra-wave 2-deep pipeline at launch_bounds(256,1).
// R22 proved 1 wave/SIMD runs ~129k cy/wave vs ~30k cy critical work with
// VGPR=200/no-spill -> stall is INTRA-wave dependency exposure, and the one
// untested fix (R19: softmax(t) VALU ∥ QKT(t+1) MFMA) only ever failed by
// SPILLING at (256,2)'s 256-reg cap. At (256,1) the 512-reg budget holds the
// pipeline's ~220 live regs easily. Flash = R19 verbatim except bounds.
// Refuted to date: LDS-BW, conflicts, barriers, occupancy, HBM, feed-BW,
// stagger, setprio, chain-split, operand reuse. proj/combine unchanged.

#define BATCH 4
#define CH    128
#define NTOK  4096
#define SCALE 0.08838834764831845f   // 1/sqrt(128)
#define LOG2E 1.4426950408889634f
#define MFIX  16.0f                  // fixed softmax offset (log2 units)

typedef __attribute__((ext_vector_type(8)))  short short8;
typedef __attribute__((ext_vector_type(4)))  float f32x4;
typedef __attribute__((ext_vector_type(16))) float f32x16;

static __device__ __forceinline__ unsigned short f2bf(float f) {
    __hip_bfloat16 h = (__hip_bfloat16)f;
    return *(const unsigned short*)&h;
}

static __device__ __forceinline__ unsigned cvt_pk_bf16(float lo, float hi) {
    unsigned r;
    asm("v_cvt_pk_bf16_f32 %0, %1, %2" : "=v"(r) : "v"(lo), "v"(hi));
    return r;
}

static __device__ __forceinline__ short8 pack_bf16x8(float4 a, float4 b) {
    union { unsigned u[4]; short8 s8; } f;
    f.u[0] = cvt_pk_bf16(a.x, a.y);
    f.u[1] = cvt_pk_bf16(a.z, a.w);
    f.u[2] = cvt_pk_bf16(b.x, b.y);
    f.u[3] = cvt_pk_bf16(b.z, b.w);
    return f.s8;
}

// ---------------- MFMA QKV projection (W-in-LDS; K,V -> fragment order) ----
// K frags: ushort[B][NTOK/32][8 ks][64 lane][8j], lane=(tok&31)+32*((ch>>3)&1),
//          ks=ch>>4, j=ch&7.   (verified R15/R16)
// V frags: ushort[B][NTOK/32][2 g][4 ct][64 lane][8j], ct=ch>>5,
//          lane=(ch&31)+32*((tok>>3)&1), g=(tok>>4)&1, j=tok&7. (verified R16)
__global__ __launch_bounds__(256) void proj_mfma_kernel(
    const float* __restrict__ x,
    const float* __restrict__ Wq, const float* __restrict__ Wk,
    const float* __restrict__ Wv,
    const float* __restrict__ bq, const float* __restrict__ bk,
    const float* __restrict__ bv,
    unsigned short* __restrict__ q_ws, unsigned short* __restrict__ kf_ws,
    unsigned short* __restrict__ vf_ws)
{
    __shared__ __align__(16) unsigned short Wl[CH * CH];   // 32 KB, swizzled
    __shared__ __align__(16) unsigned short XsT[64 * CH];  // 16 KB, swizzled

    const int t    = threadIdx.x;
    const int w    = t >> 6;
    const int lane = t & 63;
    const int quad = lane >> 4;
    const int c16  = lane & 15;
    const int n0   = blockIdx.x * 64;
    const int b    = blockIdx.y;
    const int z    = blockIdx.z;          // 0=Q, 1=K, 2=V
    const float* xb = x + (size_t)b * CH * NTOK;
    const float* wm = (z == 0) ? Wq : (z == 1) ? Wk : Wv;

    #pragma unroll
    for (int i = 0; i < 8; ++i) {
        const int f   = i * 256 + t;
        const int row = f >> 4;
        const int u   = f & 15;
        const float* src = wm + f * 8;
        const float4 a = *(const float4*)src;
        const float4 c = *(const float4*)(src + 4);
        *(short8*)&Wl[row * CH + ((u ^ (row & 15)) << 3)] = pack_bf16x8(a, c);
    }
    {
        const int tok = lane;
        #pragma unroll
        for (int cc = 0; cc < 4; ++cc) {
            const int cb = 32 * w + 8 * cc;
            float xv[8];
            #pragma unroll
            for (int j = 0; j < 8; ++j)
                xv[j] = xb[(size_t)(cb + j) * NTOK + n0 + tok];
            union { unsigned u[4]; short8 s8; } pk;
            #pragma unroll
            for (int j = 0; j < 4; ++j)
                pk.u[j] = cvt_pk_bf16(xv[2 * j], xv[2 * j + 1]);
            const int phys = ((cb >> 3) ^ (tok & 15));
            *(short8*)&XsT[tok * CH + phys * 8] = pk.s8;
        }
    }
    __syncthreads();

    if (z < 2) {
        const float* bias = (z == 0) ? bq : bk;
        const float mul = (z == 0) ? (SCALE * LOG2E) : 1.0f;
        short8 xa[4];
        #pragma unroll
        for (int ks = 0; ks < 4; ++ks)
            xa[ks] = *(const short8*)&XsT[(16 * w + c16) * CH + (((4 * ks + quad) ^ c16) << 3)];
        #pragma unroll
        for (int nt = 0; nt < 8; ++nt) {
            f32x4 a = (f32x4){0.f, 0.f, 0.f, 0.f};
            #pragma unroll
            for (int ks = 0; ks < 4; ++ks) {
                const short8 bf = *(const short8*)
                    &Wl[(16 * nt + c16) * CH + (((4 * ks + quad) ^ c16) << 3)];
                a = __builtin_amdgcn_mfma_f32_16x16x32_bf16(xa[ks], bf, a, 0, 0, 0);
            }
            const float bvv = bias[16 * nt + c16];
            #pragma unroll
            for (int r = 0; r < 4; ++r) {
                const int n = n0 + 16 * w + quad * 4 + r;
                if (z == 0) {
                    q_ws[((size_t)b * NTOK + n) * CH + 16 * nt + c16] =
                        f2bf((a[r] + bvv) * mul);
                } else {
                    const size_t idx =
                        (((size_t)b * (NTOK >> 5) + (n >> 5)) * 8 + nt) * 512
                        + ((n & 31) + 32 * (c16 >> 3)) * 8 + (c16 & 7);
                    kf_ws[idx] = f2bf(a[r] + bvv);
                }
            }
        }
    } else {
        #pragma unroll
        for (int nt = 0; nt < 4; ++nt) {
            short8 xbf[4];
            #pragma unroll
            for (int ks = 0; ks < 4; ++ks)
                xbf[ks] = *(const short8*)&XsT[(16 * nt + c16) * CH + (((4 * ks + quad) ^ c16) << 3)];
            #pragma unroll
            for (int mt = 0; mt < 2; ++mt) {
                const int crow16 = 16 * (2 * w + mt);
                f32x4 acc = (f32x4){0.f, 0.f, 0.f, 0.f};
                #pragma unroll
                for (int ks = 0; ks < 4; ++ks) {
                    const short8 wva = *(const short8*)
                        &Wl[(crow16 + c16) * CH + (((4 * ks + quad) ^ c16) << 3)];
                    acc = __builtin_amdgcn_mfma_f32_16x16x32_bf16(wva, xbf[ks], acc, 0, 0, 0);
                }
                #pragma unroll
                for (int r = 0; r < 4; ++r) {
                    const int ch  = crow16 + quad * 4 + r;
                    const int tok = n0 + 16 * nt + c16;
                    const size_t idx =
                        ((((size_t)b * (NTOK >> 5) + (tok >> 5)) * 2
                          + ((tok >> 4) & 1)) * 4 + (ch >> 5)) * 512
                        + ((ch & 31) + 32 * ((tok >> 3) & 1)) * 8 + (tok & 7);
                    vf_ws[idx] = f2bf(acc[r] + bv[ch]);
                }
            }
        }
    }
}

// ---------------- barrier-free flash, 2-deep pipeline @ 1 wave/SIMD --------
// 4 waves x 32 q-rows, independent (no LDS/barriers). Steady body per tile:
// {softmax(sX) VALU ∥ sY=QKT(t+1) MFMA} -> KF_LOAD(t+2) -> PV(t) ->
// VF_LOAD(t+1) -> sX=sY. ~220 live regs, 512 budget at (256,1): no spill.
template <int SPLIT>
__global__ __launch_bounds__(256, 1) void flash_attn_mfma(
    const unsigned short* __restrict__ q_ws,
    const unsigned short* __restrict__ kf_ws,
    const unsigned short* __restrict__ vf_ws,
    float* __restrict__ out,
    float* __restrict__ Op, float* __restrict__ l_p)
{
    const int t    = threadIdx.x;
    const int w    = t >> 6;
    const int lane = t & 63;
    const int half = lane >> 5;
    const int l32  = lane & 31;

    int xx, jc, b;
    if constexpr (SPLIT % 2 == 0) {
        // bijective XCD batch-affinity swizzle: batch b -> XCDs {2b, 2b+1}
        const int bid = blockIdx.x;
        b = (bid & 7) >> 1;
        const int sub = (bid & 1) * (16 * SPLIT) + (bid >> 3);
        jc = sub >> 5;
        xx = sub & 31;
    } else {
        const int bid = blockIdx.x;
        xx = bid & 31;
        jc = 0;
        b  = bid >> 5;
    }

    const int n0   = xx * 128;
    const int jbeg = jc * (NTOK / SPLIT);
    constexpr int NT2 = (NTOK / SPLIT) / 32;   // 32-token tiles
    static_assert(NT2 >= 2, "pipeline needs >= 2 tiles");

    const unsigned short* kg = kf_ws + (size_t)b * NTOK * CH;
    const unsigned short* vg = vf_ws + (size_t)b * NTOK * CH;

    // Q B-frags: B[k=ch][n=q=l32]
    short8 qa[8];
    {
        const unsigned short* qrow =
            q_ws + ((size_t)b * NTOK + n0 + 32 * w + l32) * CH;
        #pragma unroll
        for (int ks = 0; ks < 8; ++ks)
            qa[ks] = *(const short8*)(qrow + ks * 16 + half * 8);
    }

    f32x16 Oa[4];  // O^T tiles, D[m=ch 32ct..][n=q]
    #pragma unroll
    for (int ct = 0; ct < 4; ++ct) Oa[ct] = (f32x16)(0.0f);
    float lsum = 0.f;

    short8 kf[8];
    short8 vfA[4], vfB[4];

    auto KF_LOAD = [&](int jj) {
        const unsigned short* kb = kg + (size_t)(jj >> 5) * (8 * 512);
        #pragma unroll
        for (int ks = 0; ks < 8; ++ks)
            kf[ks] = *(const short8*)(kb + (ks * 64 + lane) * 8);
    };
    auto VF_LOAD = [&](int jj) {
        const unsigned short* vb = vg + (size_t)(jj >> 5) * (8 * 512);
        #pragma unroll
        for (int ct = 0; ct < 4; ++ct)
            vfA[ct] = *(const short8*)(vb + ((0 * 4 + ct) * 64 + lane) * 8);
        #pragma unroll
        for (int ct = 0; ct < 4; ++ct)
            vfB[ct] = *(const short8*)(vb + ((1 * 4 + ct) * 64 + lane) * 8);
    };
    auto QKT = [&](f32x16& s) {
        #pragma unroll
        for (int ks = 0; ks < 8; ++ks)
            s = __builtin_amdgcn_mfma_f32_32x32x16_bf16(kf[ks], qa[ks], s, 0, 0, 0);
    };
    auto SOFTMAX = [&](const f32x16& s, short8& pb0, short8& pb1) {
        float p[16];
        #pragma unroll
        for (int r = 0; r < 16; ++r) p[r] = exp2f(s[r]);
        float a0 = 0.f, a1 = 0.f, a2 = 0.f, a3 = 0.f;
        #pragma unroll
        for (int r = 0; r < 4; ++r) {
            a0 += p[r]; a1 += p[4 + r]; a2 += p[8 + r]; a3 += p[12 + r];
        }
        lsum += (a0 + a1) + (a2 + a3);
        unsigned wd[8];
        #pragma unroll
        for (int i = 0; i < 8; ++i) wd[i] = cvt_pk_bf16(p[2 * i], p[2 * i + 1]);
        auto r02 = __builtin_amdgcn_permlane32_swap(wd[0], wd[2], false, false);
        auto r13 = __builtin_amdgcn_permlane32_swap(wd[1], wd[3], false, false);
        auto r46 = __builtin_amdgcn_permlane32_swap(wd[4], wd[6], false, false);
        auto r57 = __builtin_amdgcn_permlane32_swap(wd[5], wd[7], false, false);
        union { unsigned u[4]; short8 s8; } f0, f1;
        f0.u[0] = r02[0]; f0.u[1] = r13[0]; f0.u[2] = r02[1]; f0.u[3] = r13[1];
        f1.u[0] = r46[0]; f1.u[1] = r57[0]; f1.u[2] = r46[1]; f1.u[3] = r57[1];
        pb0 = f0.s8;
        pb1 = f1.s8;
    };
    auto PV = [&](const short8& pb0, const short8& pb1) {
        #pragma unroll
        for (int ct = 0; ct < 4; ++ct)
            Oa[ct] = __builtin_amdgcn_mfma_f32_32x32x16_bf16(vfA[ct], pb0, Oa[ct], 0, 0, 0);
        #pragma unroll
        for (int ct = 0; ct < 4; ++ct)
            Oa[ct] = __builtin_amdgcn_mfma_f32_32x32x16_bf16(vfB[ct], pb1, Oa[ct], 0, 0, 0);
    };

    // ---- pipeline prologue: sX = QKT(tile 0); kf(1), vf(0) in flight ----
    KF_LOAD(jbeg);
    f32x16 sX = (f32x16)(-MFIX);
    QKT(sX);
    KF_LOAD(jbeg + 32);
    VF_LOAD(jbeg);

    // ---- steady state: tiles 0 .. NT2-2 ----
    int j0 = jbeg;
    for (int tt = 0; tt + 1 < NT2; ++tt, j0 += 32) {
        short8 pb0, pb1;
        // softmax(t) [VALU] and QKT(t+1) [MFMA] are independent -> the
        // scheduler interleaves them inside this wave.
        f32x16 sY = (f32x16)(-MFIX);
        SOFTMAX(sX, pb0, pb1);
        QKT(sY);
        if (tt + 2 < NT2) KF_LOAD(j0 + 64);   // uniform branch
        PV(pb0, pb1);                          // consumes vf(t)
        VF_LOAD(j0 + 32);                      // vf(t+1), covered by next phase
        sX = sY;
    }

    // ---- epilogue: last tile ----
    {
        short8 pb0, pb1;
        SOFTMAX(sX, pb0, pb1);
        PV(pb0, pb1);
    }

    // --- epilogue: l lane-local; stores coalesced (lane = token) ---
    const float lt = lsum + __shfl_xor(lsum, 32);
    const int n = n0 + 32 * w + l32;

    if constexpr (SPLIT == 1) {
        const float inv = 1.0f / lt;
        #pragma unroll
        for (int ct = 0; ct < 4; ++ct) {
            #pragma unroll
            for (int r = 0; r < 16; ++r) {
                const int c = 32 * ct + (r & 3) + 8 * (r >> 2) + 4 * half;
                out[((size_t)b * CH + c) * NTOK + n] = Oa[ct][r] * inv;
            }
        }
    } else {
        const size_t chunk = (size_t)(b * SPLIT + jc);
        #pragma unroll
        for (int ct = 0; ct < 4; ++ct) {
            #pragma unroll
            for (int r = 0; r < 16; ++r) {
                const int c = 32 * ct + (r & 3) + 8 * (r >> 2) + 4 * half;
                Op[(chunk * CH + c) * NTOK + n] = Oa[ct][r];
            }
        }
        if (half == 0) l_p[chunk * NTOK + n] = lt;
    }
}

// ---------------- combine partials: Op layout [chunk][C][N], coalesced -----
template <int SPLIT>
__global__ __launch_bounds__(256) void combine_kernel(
    const float* __restrict__ Op, const float* __restrict__ l_p,
    float* __restrict__ out)
{
    const int b = blockIdx.y;
    const size_t idx = ((size_t)blockIdx.x * 256 + threadIdx.x) * 4;  // in C*N
    const int c = (int)(idx >> 12);           // / NTOK
    const int n = (int)(idx & (NTOK - 1));
    float4 acc = make_float4(0.f, 0.f, 0.f, 0.f);
    float4 den = make_float4(0.f, 0.f, 0.f, 0.f);
    #pragma unroll
    for (int j = 0; j < SPLIT; ++j) {
        const size_t chunk = (size_t)(b * SPLIT + j);
        const float4 o = *(const float4*)&Op[(chunk * CH + c) * NTOK + n];
        const float4 d = *(const float4*)&l_p[chunk * NTOK + n];
        acc.x += o.x; acc.y += o.y; acc.z += o.z; acc.w += o.w;
        den.x += d.x; den.y += d.y; den.z += d.z; den.w += d.w;
    }
    float4 r;
    r.x = acc.x / den.x; r.y = acc.y / den.y;
    r.z = acc.z / den.z; r.w = acc.w / den.w;
    *(float4*)&out[((size_t)b * CH * NTOK) + idx] = r;
}

extern "C" void kernel_launch(void* const* d_in, const int* in_sizes, int n_in,
                              void* d_out, int out_size, void* d_ws, size_t ws_size,
                              hipStream_t stream) {
    const float* x  = (const float*)d_in[0];
    const float* Wq = (const float*)d_in[1];
    const float* bq = (const float*)d_in[2];
    const float* Wk = (const float*)d_in[3];
    const float* bk = (const float*)d_in[4];
    const float* Wv = (const float*)d_in[5];
    const float* bv = (const float*)d_in[6];
    float* out = (float*)d_out;

    const size_t QKV = (size_t)BATCH * NTOK * CH;
    unsigned short* q_ws  = (unsigned short*)d_ws;
    unsigned short* kf_ws = q_ws + QKV;
    unsigned short* vf_ws = kf_ws + QKV;
    float* Op = (float*)(vf_ws + QKV);

    const size_t baseBytes = 3 * QKV * 2;
    auto needBytes = [&](size_t S) {
        return baseBytes + S * BATCH * NTOK * (size_t)(CH * 4 + 4);
    };

    dim3 gp(NTOK / 64, BATCH, 3);
    proj_mfma_kernel<<<gp, 256, 0, stream>>>(x, Wq, Wk, Wv, bq, bk, bv,
                                             q_ws, kf_ws, vf_ws);

    dim3 gc(CH * NTOK / 1024, BATCH);
    if (ws_size >= needBytes(4)) {
        float* l_p = Op + (size_t)4 * BATCH * NTOK * CH;
        flash_attn_mfma<4><<<dim3(128 * 4), 256, 0, stream>>>(
            q_ws, kf_ws, vf_ws, out, Op, l_p);
        combine_kernel<4><<<gc, 256, 0, stream>>>(Op, l_p, out);
    } else {
        flash_attn_mfma<1><<<dim3(32 * BATCH), 256, 0, stream>>>(
            q_ws, kf_ws, vf_ws, out, nullptr, nullptr);
    }
}

// Round 19
// 126.452 us; speedup vs baseline: 1.2224x; 1.2224x over previous
//
#include <hip/hip_runtime.h>
#include <hip/hip_bf16.h>

// B=4, C=128, H=W=64 -> N=4096. ALL I/O FP32.
// FINAL (Round 24): exact restoration of the session-best kernel (R16,
// 126.55us total; flash 50.9us). Barrier-free zero-LDS flash: K and V in
// MFMA-fragment order in global (L2-resident), 32-token half-tiles, all
// operands in registers, no LDS/barriers/manual waitcnt; XCD batch-affinity
// swizzle (batch b -> XCDs {2b,2b+1}); SPLIT=4 + combine. proj: W-in-LDS
// MFMA with in-register fp32->bf16 cvt_pk, z-split {Q,K,V}.
// Plateau evidence (R7-R23): flash pinned ~51us (~490cy per 32x32 softmax-
// tile unit per CU) across LDS/L2 feed, occupancy 1-4 blocks/CU, barriers/
// none, stagger, setprio, chain-split, 2x operand reuse, 2-deep pipeline --
// every counter-visible resource individually slack; remaining gap is the
// per-tile dependency chain (QKT -> exp2 -> pack -> PV), structural at this
// problem size with fp32 I/O.

#define BATCH 4
#define CH    128
#define NTOK  4096
#define SCALE 0.08838834764831845f   // 1/sqrt(128)
#define LOG2E 1.4426950408889634f
#define MFIX  16.0f                  // fixed softmax offset (log2 units)

typedef __attribute__((ext_vector_type(8)))  short short8;
typedef __attribute__((ext_vector_type(4)))  float f32x4;
typedef __attribute__((ext_vector_type(16))) float f32x16;

static __device__ __forceinline__ unsigned short f2bf(float f) {
    __hip_bfloat16 h = (__hip_bfloat16)f;
    return *(const unsigned short*)&h;
}

static __device__ __forceinline__ unsigned cvt_pk_bf16(float lo, float hi) {
    unsigned r;
    asm("v_cvt_pk_bf16_f32 %0, %1, %2" : "=v"(r) : "v"(lo), "v"(hi));
    return r;
}

static __device__ __forceinline__ short8 pack_bf16x8(float4 a, float4 b) {
    union { unsigned u[4]; short8 s8; } f;
    f.u[0] = cvt_pk_bf16(a.x, a.y);
    f.u[1] = cvt_pk_bf16(a.z, a.w);
    f.u[2] = cvt_pk_bf16(b.x, b.y);
    f.u[3] = cvt_pk_bf16(b.z, b.w);
    return f.s8;
}

// ---------------- MFMA QKV projection (W-in-LDS; K,V -> fragment order) ----
// K frags: ushort[B][NTOK/32][8 ks][64 lane][8j], lane=(tok&31)+32*((ch>>3)&1),
//          ks=ch>>4, j=ch&7.   (verified R15/R16)
// V frags: ushort[B][NTOK/32][2 g][4 ct][64 lane][8j], ct=ch>>5,
//          lane=(ch&31)+32*((tok>>3)&1), g=(tok>>4)&1, j=tok&7. (verified R16)
__global__ __launch_bounds__(256) void proj_mfma_kernel(
    const float* __restrict__ x,
    const float* __restrict__ Wq, const float* __restrict__ Wk,
    const float* __restrict__ Wv,
    const float* __restrict__ bq, const float* __restrict__ bk,
    const float* __restrict__ bv,
    unsigned short* __restrict__ q_ws, unsigned short* __restrict__ kf_ws,
    unsigned short* __restrict__ vf_ws)
{
    __shared__ __align__(16) unsigned short Wl[CH * CH];   // 32 KB, swizzled
    __shared__ __align__(16) unsigned short XsT[64 * CH];  // 16 KB, swizzled

    const int t    = threadIdx.x;
    const int w    = t >> 6;
    const int lane = t & 63;
    const int quad = lane >> 4;
    const int c16  = lane & 15;
    const int n0   = blockIdx.x * 64;
    const int b    = blockIdx.y;
    const int z    = blockIdx.z;          // 0=Q, 1=K, 2=V
    const float* xb = x + (size_t)b * CH * NTOK;
    const float* wm = (z == 0) ? Wq : (z == 1) ? Wk : Wv;

    #pragma unroll
    for (int i = 0; i < 8; ++i) {
        const int f   = i * 256 + t;
        const int row = f >> 4;
        const int u   = f & 15;
        const float* src = wm + f * 8;
        const float4 a = *(const float4*)src;
        const float4 c = *(const float4*)(src + 4);
        *(short8*)&Wl[row * CH + ((u ^ (row & 15)) << 3)] = pack_bf16x8(a, c);
    }
    {
        const int tok = lane;
        #pragma unroll
        for (int cc = 0; cc < 4; ++cc) {
            const int cb = 32 * w + 8 * cc;
            float xv[8];
            #pragma unroll
            for (int j = 0; j < 8; ++j)
                xv[j] = xb[(size_t)(cb + j) * NTOK + n0 + tok];
            union { unsigned u[4]; short8 s8; } pk;
            #pragma unroll
            for (int j = 0; j < 4; ++j)
                pk.u[j] = cvt_pk_bf16(xv[2 * j], xv[2 * j + 1]);
            const int phys = ((cb >> 3) ^ (tok & 15));
            *(short8*)&XsT[tok * CH + phys * 8] = pk.s8;
        }
    }
    __syncthreads();

    if (z < 2) {
        const float* bias = (z == 0) ? bq : bk;
        const float mul = (z == 0) ? (SCALE * LOG2E) : 1.0f;
        short8 xa[4];
        #pragma unroll
        for (int ks = 0; ks < 4; ++ks)
            xa[ks] = *(const short8*)&XsT[(16 * w + c16) * CH + (((4 * ks + quad) ^ c16) << 3)];
        #pragma unroll
        for (int nt = 0; nt < 8; ++nt) {
            f32x4 a = (f32x4){0.f, 0.f, 0.f, 0.f};
            #pragma unroll
            for (int ks = 0; ks < 4; ++ks) {
                const short8 bf = *(const short8*)
                    &Wl[(16 * nt + c16) * CH + (((4 * ks + quad) ^ c16) << 3)];
                a = __builtin_amdgcn_mfma_f32_16x16x32_bf16(xa[ks], bf, a, 0, 0, 0);
            }
            const float bvv = bias[16 * nt + c16];
            #pragma unroll
            for (int r = 0; r < 4; ++r) {
                const int n = n0 + 16 * w + quad * 4 + r;
                if (z == 0) {
                    q_ws[((size_t)b * NTOK + n) * CH + 16 * nt + c16] =
                        f2bf((a[r] + bvv) * mul);
                } else {
                    const size_t idx =
                        (((size_t)b * (NTOK >> 5) + (n >> 5)) * 8 + nt) * 512
                        + ((n & 31) + 32 * (c16 >> 3)) * 8 + (c16 & 7);
                    kf_ws[idx] = f2bf(a[r] + bvv);
                }
            }
        }
    } else {
        #pragma unroll
        for (int nt = 0; nt < 4; ++nt) {
            short8 xbf[4];
            #pragma unroll
            for (int ks = 0; ks < 4; ++ks)
                xbf[ks] = *(const short8*)&XsT[(16 * nt + c16) * CH + (((4 * ks + quad) ^ c16) << 3)];
            #pragma unroll
            for (int mt = 0; mt < 2; ++mt) {
                const int crow16 = 16 * (2 * w + mt);
                f32x4 acc = (f32x4){0.f, 0.f, 0.f, 0.f};
                #pragma unroll
                for (int ks = 0; ks < 4; ++ks) {
                    const short8 wva = *(const short8*)
                        &Wl[(crow16 + c16) * CH + (((4 * ks + quad) ^ c16) << 3)];
                    acc = __builtin_amdgcn_mfma_f32_16x16x32_bf16(wva, xbf[ks], acc, 0, 0, 0);
                }
                #pragma unroll
                for (int r = 0; r < 4; ++r) {
                    const int ch  = crow16 + quad * 4 + r;
                    const int tok = n0 + 16 * nt + c16;
                    const size_t idx =
                        ((((size_t)b * (NTOK >> 5) + (tok >> 5)) * 2
                          + ((tok >> 4) & 1)) * 4 + (ch >> 5)) * 512
                        + ((ch & 31) + 32 * ((tok >> 3) & 1)) * 8 + (tok & 7);
                    vf_ws[idx] = f2bf(acc[r] + bv[ch]);
                }
            }
        }
    }
}

// ---------------- barrier-free split-KV flash: all operands from L2 --------
// 4 waves x 32 q-rows, fully independent (no LDS, no barriers). 32-token
// half-tiles: 8 kf + 8 vf coalesced 1KB loads, 8 QK^T + 8 PV MFMA, one
// 16-value in-register softmax. kf(t+1) prefetched after QK^T(t).
template <int SPLIT>
__global__ __launch_bounds__(256, 2) void flash_attn_mfma(
    const unsigned short* __restrict__ q_ws,
    const unsigned short* __restrict__ kf_ws,
    const unsigned short* __restrict__ vf_ws,
    float* __restrict__ out,
    float* __restrict__ Op, float* __restrict__ l_p)
{
    const int t    = threadIdx.x;
    const int w    = t >> 6;
    const int lane = t & 63;
    const int half = lane >> 5;
    const int l32  = lane & 31;

    int xx, jc, b;
    if constexpr (SPLIT == 4) {
        // bijective XCD batch-affinity swizzle: batch b -> XCDs {2b, 2b+1}
        const int bid = blockIdx.x;            // 0..511, XCD = bid & 7
        b = (bid & 7) >> 1;
        const int sub = ((bid & 1) << 6) | (bid >> 3);   // 0..127
        jc = sub >> 5;
        xx = sub & 31;
    } else {
        const int bid = blockIdx.x;
        xx = bid & 31;
        jc = (bid >> 5) % SPLIT;
        b  = bid / (32 * SPLIT);
    }

    const int n0   = xx * 128;
    const int jbeg = jc * (NTOK / SPLIT);
    constexpr int NT2 = (NTOK / SPLIT) / 32;   // 32-token half-tiles

    const unsigned short* kg = kf_ws + (size_t)b * NTOK * CH;
    const unsigned short* vg = vf_ws + (size_t)b * NTOK * CH;

    // Q B-frags: B[k=ch][n=q=l32]
    short8 qa[8];
    {
        const unsigned short* qrow =
            q_ws + ((size_t)b * NTOK + n0 + 32 * w + l32) * CH;
        #pragma unroll
        for (int ks = 0; ks < 8; ++ks)
            qa[ks] = *(const short8*)(qrow + ks * 16 + half * 8);
    }

    f32x16 Oa[4];  // O^T tiles, D[m=ch 32ct..][n=q]
    #pragma unroll
    for (int ct = 0; ct < 4; ++ct) Oa[ct] = (f32x16)(0.0f);
    float lsum = 0.f;

    short8 kf[8];
    auto KF_LOAD = [&](int jj) {
        const unsigned short* kb = kg + (size_t)(jj >> 5) * (8 * 512);
        #pragma unroll
        for (int ks = 0; ks < 8; ++ks)
            kf[ks] = *(const short8*)(kb + (ks * 64 + lane) * 8);
    };

    KF_LOAD(jbeg);

    int j0 = jbeg;
    for (int tt = 0; tt < NT2; ++tt, j0 += 32) {
        // --- S^T = K Q^T - MFIX (one 32x32 tile) ---
        f32x16 s = (f32x16)(-MFIX);
        #pragma unroll
        for (int ks = 0; ks < 8; ++ks)
            s = __builtin_amdgcn_mfma_f32_32x32x16_bf16(kf[ks], qa[ks], s, 0, 0, 0);

        // --- issue this tile's V fragments + next tile's K (kf regs free) ---
        short8 vfA[4], vfB[4];
        {
            const unsigned short* vb = vg + (size_t)(j0 >> 5) * (8 * 512);
            #pragma unroll
            for (int ct = 0; ct < 4; ++ct)
                vfA[ct] = *(const short8*)(vb + ((0 * 4 + ct) * 64 + lane) * 8);
            #pragma unroll
            for (int ct = 0; ct < 4; ++ct)
                vfB[ct] = *(const short8*)(vb + ((1 * 4 + ct) * 64 + lane) * 8);
        }
        if (tt + 1 < NT2) KF_LOAD(j0 + 32);

        // --- P = exp2(S); pack to PV B-frags via cvt_pk + permlane32_swap ---
        float p[16];
        #pragma unroll
        for (int r = 0; r < 16; ++r) p[r] = exp2f(s[r]);
        {
            float a0 = 0.f, a1 = 0.f, a2 = 0.f, a3 = 0.f;
            #pragma unroll
            for (int r = 0; r < 4; ++r) {
                a0 += p[r]; a1 += p[4 + r]; a2 += p[8 + r]; a3 += p[12 + r];
            }
            lsum += (a0 + a1) + (a2 + a3);
        }
        short8 pb0, pb1;
        {
            unsigned wd[8];
            #pragma unroll
            for (int i = 0; i < 8; ++i) wd[i] = cvt_pk_bf16(p[2 * i], p[2 * i + 1]);
            auto r02 = __builtin_amdgcn_permlane32_swap(wd[0], wd[2], false, false);
            auto r13 = __builtin_amdgcn_permlane32_swap(wd[1], wd[3], false, false);
            auto r46 = __builtin_amdgcn_permlane32_swap(wd[4], wd[6], false, false);
            auto r57 = __builtin_amdgcn_permlane32_swap(wd[5], wd[7], false, false);
            union { unsigned u[4]; short8 s8; } f0, f1;
            f0.u[0] = r02[0]; f0.u[1] = r13[0]; f0.u[2] = r02[1]; f0.u[3] = r13[1];
            f1.u[0] = r46[0]; f1.u[1] = r57[0]; f1.u[2] = r46[1]; f1.u[3] = r57[1];
            pb0 = f0.s8;
            pb1 = f1.s8;
        }

        // --- O^T += V^T P^T ---
        #pragma unroll
        for (int ct = 0; ct < 4; ++ct)
            Oa[ct] = __builtin_amdgcn_mfma_f32_32x32x16_bf16(vfA[ct], pb0, Oa[ct], 0, 0, 0);
        #pragma unroll
        for (int ct = 0; ct < 4; ++ct)
            Oa[ct] = __builtin_amdgcn_mfma_f32_32x32x16_bf16(vfB[ct], pb1, Oa[ct], 0, 0, 0);
    }

    // --- epilogue: l lane-local; stores coalesced (lane = token) ---
    const float lt = lsum + __shfl_xor(lsum, 32);
    const int n = n0 + 32 * w + l32;

    if constexpr (SPLIT == 1) {
        const float inv = 1.0f / lt;
        #pragma unroll
        for (int ct = 0; ct < 4; ++ct) {
            #pragma unroll
            for (int r = 0; r < 16; ++r) {
                const int c = 32 * ct + (r & 3) + 8 * (r >> 2) + 4 * half;
                out[((size_t)b * CH + c) * NTOK + n] = Oa[ct][r] * inv;
            }
        }
    } else {
        const size_t chunk = (size_t)(b * SPLIT + jc);
        #pragma unroll
        for (int ct = 0; ct < 4; ++ct) {
            #pragma unroll
            for (int r = 0; r < 16; ++r) {
                const int c = 32 * ct + (r & 3) + 8 * (r >> 2) + 4 * half;
                Op[(chunk * CH + c) * NTOK + n] = Oa[ct][r];
            }
        }
        if (half == 0) l_p[chunk * NTOK + n] = lt;
    }
}

// ---------------- combine partials: Op layout [chunk][C][N], coalesced -----
template <int SPLIT>
__global__ __launch_bounds__(256) void combine_kernel(
    const float* __restrict__ Op, const float* __restrict__ l_p,
    float* __restrict__ out)
{
    const int b = blockIdx.y;
    const size_t idx = ((size_t)blockIdx.x * 256 + threadIdx.x) * 4;  // in C*N
    const int c = (int)(idx >> 12);           // / NTOK
    const int n = (int)(idx & (NTOK - 1));
    float4 acc = make_float4(0.f, 0.f, 0.f, 0.f);
    float4 den = make_float4(0.f, 0.f, 0.f, 0.f);
    #pragma unroll
    for (int j = 0; j < SPLIT; ++j) {
        const size_t chunk = (size_t)(b * SPLIT + j);
        const float4 o = *(const float4*)&Op[(chunk * CH + c) * NTOK + n];
        const float4 d = *(const float4*)&l_p[chunk * NTOK + n];
        acc.x += o.x; acc.y += o.y; acc.z += o.z; acc.w += o.w;
        den.x += d.x; den.y += d.y; den.z += d.z; den.w += d.w;
    }
    float4 r;
    r.x = acc.x / den.x; r.y = acc.y / den.y;
    r.z = acc.z / den.z; r.w = acc.w / den.w;
    *(float4*)&out[((size_t)b * CH * NTOK) + idx] = r;
}

extern "C" void kernel_launch(void* const* d_in, const int* in_sizes, int n_in,
                              void* d_out, int out_size, void* d_ws, size_t ws_size,
                              hipStream_t stream) {
    const float* x  = (const float*)d_in[0];
    const float* Wq = (const float*)d_in[1];
    const float* bq = (const float*)d_in[2];
    const float* Wk = (const float*)d_in[3];
    const float* bk = (const float*)d_in[4];
    const float* Wv = (const float*)d_in[5];
    const float* bv = (const float*)d_in[6];
    float* out = (float*)d_out;

    const size_t QKV = (size_t)BATCH * NTOK * CH;
    unsigned short* q_ws  = (unsigned short*)d_ws;
    unsigned short* kf_ws = q_ws + QKV;
    unsigned short* vf_ws = kf_ws + QKV;
    float* Op = (float*)(vf_ws + QKV);

    const size_t baseBytes = 3 * QKV * 2;
    auto needBytes = [&](size_t S) {
        return baseBytes + S * BATCH * NTOK * (size_t)(CH * 4 + 4);
    };

    dim3 gp(NTOK / 64, BATCH, 3);
    proj_mfma_kernel<<<gp, 256, 0, stream>>>(x, Wq, Wk, Wv, bq, bk, bv,
                                             q_ws, kf_ws, vf_ws);

    dim3 gc(CH * NTOK / 1024, BATCH);
    if (ws_size >= needBytes(4)) {
        float* l_p = Op + (size_t)4 * BATCH * NTOK * CH;
        flash_attn_mfma<4><<<dim3(32 * 4 * BATCH), 256, 0, stream>>>(
            q_ws, kf_ws, vf_ws, out, Op, l_p);
        combine_kernel<4><<<gc, 256, 0, stream>>>(Op, l_p, out);
    } else {
        flash_attn_mfma<1><<<dim3(32 * BATCH), 256, 0, stream>>>(
            q_ws, kf_ws, vf_ws, out, nullptr, nullptr);
    }
}